// Round 1
// baseline (190.348 us; speedup 1.0000x reference)
//
#include <hip/hip_runtime.h>
#include <math.h>

#define D 256
#define KNB 32
#define RS 264            // padded LDS row stride in floats (8k+j bank spread)
#define NEG_SLOPE 0.2f

// ---------------------------------------------------------------------------
// prep: blocks 0..255 transpose W into Wt[f][o]; block 256 computes
// w_src[f] = sum_o a_src[o]*W[o][f], w_tgt likewise.
// ws layout (floats): [0..255]=w_src  [256..511]=w_tgt  [512..66047]=Wt
//                     [66048..86047]=scores_t
// ---------------------------------------------------------------------------
__global__ __launch_bounds__(256) void prep_kernel(
    const float* __restrict__ W, const float* __restrict__ a_src,
    const float* __restrict__ a_tgt, float* __restrict__ ws)
{
    int t = threadIdx.x;
    int b = blockIdx.x;
    float* w_src = ws;
    float* w_tgt = ws + D;
    float* Wt    = ws + 2 * D;
    if (b < D) {
        // Wt[b][t] = W[t][b]
        Wt[b * D + t] = W[t * D + b];
    } else {
        float as = 0.f, at = 0.f;
        for (int o = 0; o < D; ++o) {
            float w = W[o * D + t];
            as = fmaf(a_src[o], w, as);
            at = fmaf(a_tgt[o], w, at);
        }
        w_src[t] = as;
        w_tgt[t] = at;
    }
}

// ---------------------------------------------------------------------------
// scores_t[n] = nodes[n,:] . w_tgt   (one wave per node, 4 nodes/block)
// ---------------------------------------------------------------------------
__global__ __launch_bounds__(256) void scores_t_kernel(
    const float* __restrict__ nodes, const float* __restrict__ ws,
    float* __restrict__ scores_t, int N)
{
    const float* w_tgt = ws + D;
    int wid  = threadIdx.x >> 6;
    int lane = threadIdx.x & 63;
    int n = blockIdx.x * 4 + wid;
    if (n >= N) return;
    const float4* row = reinterpret_cast<const float4*>(nodes + (size_t)n * D);
    float4 v = row[lane];
    float4 w = reinterpret_cast<const float4*>(w_tgt)[lane];
    float s = v.x * w.x + v.y * w.y + v.z * w.z + v.w * w.w;
    #pragma unroll
    for (int off = 1; off < 64; off <<= 1) s += __shfl_xor(s, off);
    if (lane == 0) scores_t[n] = s;
}

// ---------------------------------------------------------------------------
// Fused attention + aggregate. One block (256 thr) per node.
// Stage neighbors[n] (32x256 f32 = 32KB) in LDS once; compute 32 edge scores
// (8 lanes per k), softmax (raw exp, +eps), then agg[f] = sum_k attn_k * v.
// agg written to d_out (reused as scratch; K2 rewrites in place).
// ---------------------------------------------------------------------------
__global__ __launch_bounds__(256) void attn_agg_kernel(
    const float* __restrict__ neighbors, const float* __restrict__ ws,
    const float* __restrict__ scores_t, float* __restrict__ agg, int N)
{
    __shared__ __align__(16) float sneigh[KNB * RS];
    __shared__ __align__(16) float sw[D];
    __shared__ float sp[KNB];
    __shared__ float sinv;

    int t = threadIdx.x;
    int n = blockIdx.x;

    sw[t] = ws[t];  // w_src

    const float4* g = reinterpret_cast<const float4*>(neighbors + (size_t)n * (KNB * D));
    #pragma unroll
    for (int i = 0; i < 8; ++i) {
        int v = i * 256 + t;      // float4 index into 32x256 tile
        int k = v >> 6;           // row (64 float4 per row)
        int c = (v & 63) << 2;    // float col
        *reinterpret_cast<float4*>(&sneigh[k * RS + c]) = g[v];
    }
    __syncthreads();

    // edge scores: 8 lanes per neighbor k
    int k = t >> 3, j = t & 7;
    float s = 0.f;
    #pragma unroll
    for (int i = 0; i < 32; ++i) {
        int f = j + (i << 3);
        s = fmaf(sneigh[k * RS + f], sw[f], s);
    }
    s += __shfl_xor(s, 1);
    s += __shfl_xor(s, 2);
    s += __shfl_xor(s, 4);
    if (j == 0) {
        float e = s + scores_t[n];
        e = (e >= 0.f) ? e : NEG_SLOPE * e;
        sp[k] = __expf(e);
    }
    __syncthreads();

    if (t < 64) {
        float p = (t < KNB) ? sp[t] : 0.f;
        #pragma unroll
        for (int off = 1; off < KNB; off <<= 1) p += __shfl_xor(p, off);
        if (t == 0) sinv = 1.f / (p + 1e-16f);
    }
    __syncthreads();

    float acc = 0.f;
    #pragma unroll
    for (int kk = 0; kk < KNB; ++kk)
        acc = fmaf(sp[kk], sneigh[kk * RS + t], acc);
    agg[(size_t)n * D + t] = acc * sinv;
}

// ---------------------------------------------------------------------------
// out = elu(agg @ W^T + bias), computed in place on d_out.
// TILE=32 nodes/block staged in LDS; thread (to = t&63, tj = t>>6) computes
// 8 nodes x 4 outputs using coalesced float4 reads of Wt rows.
// ---------------------------------------------------------------------------
#define TILE 32
__global__ __launch_bounds__(256) void out_kernel(
    float* __restrict__ io, const float* __restrict__ ws,
    const float* __restrict__ bias, int N)
{
    const float* Wt = ws + 2 * D;
    __shared__ __align__(16) float sa[TILE][D];

    int t = threadIdx.x;
    int n0 = blockIdx.x * TILE;

    const float4* g = reinterpret_cast<const float4*>(io + (size_t)n0 * D);
    float4* s4 = reinterpret_cast<float4*>(&sa[0][0]);
    int nvalid4 = (min(TILE, N - n0)) * (D / 4);
    #pragma unroll
    for (int i = 0; i < TILE * D / 1024; ++i) {   // 8 float4 per thread
        int v = i * 256 + t;
        s4[v] = (v < nvalid4) ? g[v] : make_float4(0.f, 0.f, 0.f, 0.f);
    }
    __syncthreads();

    int to = t & 63;        // output group: o = 4*to .. 4*to+3
    int tj = t >> 6;        // node group: nodes tj*8 .. tj*8+7
    const float4* wt4 = reinterpret_cast<const float4*>(Wt);

    float4 acc[8];
    #pragma unroll
    for (int jj = 0; jj < 8; ++jj) acc[jj] = make_float4(0.f, 0.f, 0.f, 0.f);

    for (int f = 0; f < D; ++f) {
        float4 wv = wt4[f * (D / 4) + to];
        #pragma unroll
        for (int jj = 0; jj < 8; ++jj) {
            float a = sa[tj * 8 + jj][f];
            acc[jj].x = fmaf(a, wv.x, acc[jj].x);
            acc[jj].y = fmaf(a, wv.y, acc[jj].y);
            acc[jj].z = fmaf(a, wv.z, acc[jj].z);
            acc[jj].w = fmaf(a, wv.w, acc[jj].w);
        }
    }

    float4 b = reinterpret_cast<const float4*>(bias)[to];
    #pragma unroll
    for (int jj = 0; jj < 8; ++jj) {
        int n = n0 + tj * 8 + jj;
        if (n < N) {
            float4 x;
            x.x = acc[jj].x + b.x;
            x.y = acc[jj].y + b.y;
            x.z = acc[jj].z + b.z;
            x.w = acc[jj].w + b.w;
            x.x = (x.x > 0.f) ? x.x : expm1f(x.x);
            x.y = (x.y > 0.f) ? x.y : expm1f(x.y);
            x.z = (x.z > 0.f) ? x.z : expm1f(x.z);
            x.w = (x.w > 0.f) ? x.w : expm1f(x.w);
            reinterpret_cast<float4*>(io + (size_t)n * D)[to] = x;
        }
    }
}

// ---------------------------------------------------------------------------
extern "C" void kernel_launch(void* const* d_in, const int* in_sizes, int n_in,
                              void* d_out, int out_size, void* d_ws, size_t ws_size,
                              hipStream_t stream) {
    const float* nodes     = (const float*)d_in[0];
    const float* neighbors = (const float*)d_in[1];
    const float* W         = (const float*)d_in[2];
    const float* a_src     = (const float*)d_in[3];
    const float* a_tgt     = (const float*)d_in[4];
    const float* bias      = (const float*)d_in[5];
    float* out = (float*)d_out;
    float* ws  = (float*)d_ws;

    int N = in_sizes[0] / D;                    // 20000
    float* scores_t = ws + 2 * D + D * D;       // 20000 floats

    hipLaunchKernelGGL(prep_kernel, dim3(D + 1), dim3(256), 0, stream,
                       W, a_src, a_tgt, ws);
    hipLaunchKernelGGL(scores_t_kernel, dim3((N + 3) / 4), dim3(256), 0, stream,
                       nodes, ws, scores_t, N);
    hipLaunchKernelGGL(attn_agg_kernel, dim3(N), dim3(256), 0, stream,
                       neighbors, ws, scores_t, out, N);
    hipLaunchKernelGGL(out_kernel, dim3((N + TILE - 1) / TILE), dim3(256), 0, stream,
                       out, ws, bias, N);
}

// Round 2
// 184.872 us; speedup vs baseline: 1.0296x; 1.0296x over previous
//
#include <hip/hip_runtime.h>
#include <hip/hip_bf16.h>
#include <math.h>

#define D 256
#define KNB 32
#define NEG_SLOPE 0.2f

using bfrag = __attribute__((ext_vector_type(8))) short;   // 8 bf16 (4 VGPR)
using ffrag = __attribute__((ext_vector_type(4))) float;   // 4 f32 acc

__device__ __forceinline__ unsigned short f2bf(float x) {
    __hip_bfloat16 h = __float2bfloat16(x);
    return *reinterpret_cast<unsigned short*>(&h);
}

// ---------------------------------------------------------------------------
// prep: blocks 0..63 convert W (f32 [256][256]) -> Wbf (bf16, same layout).
// block 64: w_src[f]=sum_o a_src[o]W[o][f], w_tgt likewise.
// ws layout (floats): [0..255]=w_src  [256..511]=w_tgt
//                     [512..33279]=Wbf (65536 bf16)
//                     [33280.. ]=agg_bf (20000*256 bf16 = 2,560,000 floats)
// ---------------------------------------------------------------------------
__global__ __launch_bounds__(256) void prep_kernel(
    const float* __restrict__ W, const float* __restrict__ a_src,
    const float* __restrict__ a_tgt, float* __restrict__ ws)
{
    int t = threadIdx.x;
    int b = blockIdx.x;
    if (b < 64) {
        const float4* w4 = reinterpret_cast<const float4*>(W);
        float4 v = w4[b * 256 + t];
        ushort4 u;
        u.x = f2bf(v.x); u.y = f2bf(v.y); u.z = f2bf(v.z); u.w = f2bf(v.w);
        reinterpret_cast<ushort4*>(ws + 512)[b * 256 + t] = u;
    } else {
        float as = 0.f, at = 0.f;
        for (int o = 0; o < D; ++o) {
            float w = W[o * D + t];
            as = fmaf(a_src[o], w, as);
            at = fmaf(a_tgt[o], w, at);
        }
        ws[t]     = as;   // w_src
        ws[D + t] = at;   // w_tgt
    }
}

// ---------------------------------------------------------------------------
// Fused scores_t + attention + aggregate. One block (256 thr) per node.
// Score partials computed DURING the staging loads (register-resident),
// so the post-barrier phase is only the 32-step weighted sum.
// Output agg in bf16 -> ws.
// ---------------------------------------------------------------------------
__global__ __launch_bounds__(256) void attn_agg_kernel(
    const float* __restrict__ nodes, const float* __restrict__ neighbors,
    const float* __restrict__ ws, unsigned short* __restrict__ aggbf, int N)
{
    __shared__ __align__(16) float sn[KNB][D];   // 32 KB
    __shared__ float sp[KNB];

    int t = threadIdx.x;
    int n = blockIdx.x;
    int lane = t & 63, w = t >> 6;

    // per-thread w_src chunk (f4 = t&63 is constant across the 8 staged loads)
    float4 wsv = reinterpret_cast<const float4*>(ws)[t & 63];

    // scores_t[n] = nodes[n,:] . w_tgt  (each wave computes the full dot)
    float4 nv  = reinterpret_cast<const float4*>(nodes + (size_t)n * D)[lane];
    float4 wtv = reinterpret_cast<const float4*>(ws + D)[lane];
    float st = nv.x * wtv.x + nv.y * wtv.y + nv.z * wtv.z + nv.w * wtv.w;
    #pragma unroll
    for (int o = 1; o < 64; o <<= 1) st += __shfl_xor(st, o);

    // stage 32x256 f32 tile; fuse w_src dot-partials.
    // v = i*256+t -> k = i*4 + (t>>6), f4 = t&63
    const float4* g = reinterpret_cast<const float4*>(neighbors + (size_t)n * (KNB * D));
    float4* s4 = reinterpret_cast<float4*>(&sn[0][0]);
    float pk[8];
    #pragma unroll
    for (int i = 0; i < 8; ++i) {
        float4 x = g[i * 256 + t];
        s4[i * 256 + t] = x;
        pk[i] = x.x * wsv.x + x.y * wsv.y + x.z * wsv.z + x.w * wsv.w;
    }
    #pragma unroll
    for (int i = 0; i < 8; ++i) {
        #pragma unroll
        for (int o = 1; o < 64; o <<= 1) pk[i] += __shfl_xor(pk[i], o);
    }
    if (lane == 0) {
        #pragma unroll
        for (int i = 0; i < 8; ++i) {      // wave w owns k = i*4 + w
            float e = pk[i] + st;
            e = (e >= 0.f) ? e : NEG_SLOPE * e;
            sp[i * 4 + w] = __expf(e);
        }
    }
    __syncthreads();

    float sum = 0.f, acc = 0.f;
    #pragma unroll
    for (int k = 0; k < KNB; ++k) {
        float p = sp[k];                   // LDS broadcast
        sum += p;
        acc = fmaf(p, sn[k][t], acc);      // conflict-free column read
    }
    float r = acc / (sum + 1e-16f);
    aggbf[(size_t)n * D + t] = f2bf(r);
}

// ---------------------------------------------------------------------------
// out = elu(agg_bf @ Wbf^T + bias), f32 out. One wave per block, 16 rows.
// mfma_f32_16x16x32_bf16: A lane l: row=l&15, k=(l>>4)*8+j (8 consecutive k)
//                         B lane l: col=l&15, k=(l>>4)*8+j
//                         D lane l: row=(l>>4)*4+reg, col=l&15
// ---------------------------------------------------------------------------
__global__ __launch_bounds__(64) void out_gemm_kernel(
    const unsigned short* __restrict__ aggbf,
    const unsigned short* __restrict__ wbf,
    const float* __restrict__ bias, float* __restrict__ out, int N)
{
    int l = threadIdx.x;
    int m0 = blockIdx.x * 16;
    if (m0 >= N) return;
    int lr = l & 15, lk = l >> 4;

    ffrag acc[16];
    #pragma unroll
    for (int nf = 0; nf < 16; ++nf) acc[nf] = ffrag{0.f, 0.f, 0.f, 0.f};

    #pragma unroll
    for (int ks = 0; ks < 8; ++ks) {
        bfrag a = *reinterpret_cast<const bfrag*>(
            aggbf + (size_t)(m0 + lr) * D + ks * 32 + lk * 8);
        #pragma unroll
        for (int nf = 0; nf < 16; ++nf) {
            bfrag b = *reinterpret_cast<const bfrag*>(
                wbf + (size_t)(nf * 16 + lr) * D + ks * 32 + lk * 8);
            acc[nf] = __builtin_amdgcn_mfma_f32_16x16x32_bf16(a, b, acc[nf], 0, 0, 0);
        }
    }

    #pragma unroll
    for (int nf = 0; nf < 16; ++nf) {
        int col = nf * 16 + lr;
        float bv = bias[col];
        #pragma unroll
        for (int r = 0; r < 4; ++r) {
            int m = m0 + lk * 4 + r;
            float x = acc[nf][r] + bv;
            x = (x > 0.f) ? x : expm1f(x);
            out[(size_t)m * D + col] = x;
        }
    }
}

// ---------------------------------------------------------------------------
extern "C" void kernel_launch(void* const* d_in, const int* in_sizes, int n_in,
                              void* d_out, int out_size, void* d_ws, size_t ws_size,
                              hipStream_t stream) {
    const float* nodes     = (const float*)d_in[0];
    const float* neighbors = (const float*)d_in[1];
    const float* W         = (const float*)d_in[2];
    const float* a_src     = (const float*)d_in[3];
    const float* a_tgt     = (const float*)d_in[4];
    const float* bias      = (const float*)d_in[5];
    float* out = (float*)d_out;
    float* ws  = (float*)d_ws;

    int N = in_sizes[0] / D;                                 // 20000
    unsigned short* wbf   = (unsigned short*)(ws + 512);     // 65536 bf16
    unsigned short* aggbf = (unsigned short*)(ws + 33280);   // N*256 bf16

    hipLaunchKernelGGL(prep_kernel, dim3(65), dim3(256), 0, stream,
                       W, a_src, a_tgt, ws);
    hipLaunchKernelGGL(attn_agg_kernel, dim3(N), dim3(256), 0, stream,
                       nodes, neighbors, ws, aggbf, N);
    hipLaunchKernelGGL(out_gemm_kernel, dim3(N / 16), dim3(64), 0, stream,
                       aggbf, wbf, bias, out, N);
}